// Round 1
// baseline (95.859 us; speedup 1.0000x reference)
//
#include <hip/hip_runtime.h>
#include <math.h>

#define HH 1024
#define WW 1024
#define BB 32
#define HW (HH*WW)                 // 1048576 pixels per sample
#define CHUNKS 64                  // blocks per sample
#define PIXB (HW/CHUNKS)           // 16384 pixels per block
#define THREADS 256
#define ITERS (PIXB/4/THREADS)     // 16 float4 iterations per thread

struct WsLayout {
    float cel_part[BB*CHUNKS];     // 2048 deterministic per-block partials
    unsigned int tcnt[BB];         // per-sample trans count
    unsigned int gcnt[BB];         // per-sample gt==1 count
    int trmin[BB], trmax[BB], tcmin[BB], tcmax[BB];   // trans bbox
    int grmin[BB], grmax[BB], gcmin[BB], gcmax[BB];   // gt bbox
};

__global__ void init_ws(WsLayout* ws) {
    int t = blockIdx.x * blockDim.x + threadIdx.x;
    if (t < BB*CHUNKS) ws->cel_part[t] = 0.0f;
    if (t < BB) {
        ws->tcnt[t] = 0u;  ws->gcnt[t] = 0u;
        ws->trmin[t] = HH; ws->trmax[t] = -1;
        ws->tcmin[t] = WW; ws->tcmax[t] = -1;
        ws->grmin[t] = HH; ws->grmax[t] = -1;
        ws->gcmin[t] = WW; ws->gcmax[t] = -1;
    }
}

__global__ __launch_bounds__(THREADS) void wnet_main(
        const float* __restrict__ x, const int* __restrict__ gt,
        WsLayout* __restrict__ ws) {
    const int blk   = blockIdx.x;
    const int b     = blk >> 6;        // / CHUNKS
    const int chunk = blk & 63;
    const float4* __restrict__ x0 = reinterpret_cast<const float4*>(x + (size_t)b * 2 * HW);
    const float4* __restrict__ x1 = reinterpret_cast<const float4*>(x + (size_t)b * 2 * HW + HW);
    const int4*   __restrict__ g  = reinterpret_cast<const int4*>(gt + (size_t)b * HW);
    const int base4 = chunk * (PIXB/4);

    float cel = 0.0f;
    unsigned int tc = 0u, gc = 0u;
    int trmin = HH, trmax = -1, tcmin = WW, tcmax = -1;
    int grmin = HH, grmax = -1, gcmin = WW, gcmax = -1;

    #pragma unroll 4
    for (int it = 0; it < ITERS; ++it) {
        const int idx4 = base4 + it*THREADS + threadIdx.x;
        float4 a  = x0[idx4];
        float4 c  = x1[idx4];
        int4   gv = g[idx4];
        const int p  = idx4 << 2;          // first pixel of this float4
        const int h  = p >> 10;            // row (W=1024)
        const int w0 = p & 1023;           // col of lane-element 0

        float xa[4] = {a.x, a.y, a.z, a.w};
        float xc[4] = {c.x, c.y, c.z, c.w};
        int   gg[4] = {gv.x, gv.y, gv.z, gv.w};

        #pragma unroll
        for (int j = 0; j < 4; ++j) {
            const bool trans = xc[j] > xa[j];
            const bool gm    = (gg[j] == 1);
            // cel: softplus(x_other - x_gt), stable form
            const float d = gm ? (xa[j] - xc[j]) : (xc[j] - xa[j]);
            cel += fmaxf(d, 0.0f) + __logf(1.0f + __expf(-fabsf(d)));
            tc += trans ? 1u : 0u;
            gc += gm    ? 1u : 0u;
            const int w = w0 + j;
            trmin = min(trmin, trans ? h : HH);
            trmax = max(trmax, trans ? h : -1);
            tcmin = min(tcmin, trans ? w : WW);
            tcmax = max(tcmax, trans ? w : -1);
            grmin = min(grmin, gm ? h : HH);
            grmax = max(grmax, gm ? h : -1);
            gcmin = min(gcmin, gm ? w : WW);
            gcmax = max(gcmax, gm ? w : -1);
        }
    }

    // ---- wave (64-lane) reduction ----
    #pragma unroll
    for (int o = 32; o > 0; o >>= 1) {
        cel  += __shfl_down(cel, o);
        tc   += __shfl_down(tc, o);
        gc   += __shfl_down(gc, o);
        trmin = min(trmin, __shfl_down(trmin, o));
        trmax = max(trmax, __shfl_down(trmax, o));
        tcmin = min(tcmin, __shfl_down(tcmin, o));
        tcmax = max(tcmax, __shfl_down(tcmax, o));
        grmin = min(grmin, __shfl_down(grmin, o));
        grmax = max(grmax, __shfl_down(grmax, o));
        gcmin = min(gcmin, __shfl_down(gcmin, o));
        gcmax = max(gcmax, __shfl_down(gcmax, o));
    }

    // ---- cross-wave (4 waves) via LDS ----
    __shared__ float s_cel[4];
    __shared__ unsigned int s_tc[4], s_gc[4];
    __shared__ int s_trmin[4], s_trmax[4], s_tcmin[4], s_tcmax[4];
    __shared__ int s_grmin[4], s_grmax[4], s_gcmin[4], s_gcmax[4];
    const int wid  = threadIdx.x >> 6;
    const int lane = threadIdx.x & 63;
    if (lane == 0) {
        s_cel[wid] = cel;  s_tc[wid] = tc;  s_gc[wid] = gc;
        s_trmin[wid] = trmin; s_trmax[wid] = trmax;
        s_tcmin[wid] = tcmin; s_tcmax[wid] = tcmax;
        s_grmin[wid] = grmin; s_grmax[wid] = grmax;
        s_gcmin[wid] = gcmin; s_gcmax[wid] = gcmax;
    }
    __syncthreads();
    if (threadIdx.x == 0) {
        float celT = s_cel[0] + s_cel[1] + s_cel[2] + s_cel[3];
        unsigned int tcT = s_tc[0] + s_tc[1] + s_tc[2] + s_tc[3];
        unsigned int gcT = s_gc[0] + s_gc[1] + s_gc[2] + s_gc[3];
        int a1 = min(min(s_trmin[0], s_trmin[1]), min(s_trmin[2], s_trmin[3]));
        int a2 = max(max(s_trmax[0], s_trmax[1]), max(s_trmax[2], s_trmax[3]));
        int a3 = min(min(s_tcmin[0], s_tcmin[1]), min(s_tcmin[2], s_tcmin[3]));
        int a4 = max(max(s_tcmax[0], s_tcmax[1]), max(s_tcmax[2], s_tcmax[3]));
        int a5 = min(min(s_grmin[0], s_grmin[1]), min(s_grmin[2], s_grmin[3]));
        int a6 = max(max(s_grmax[0], s_grmax[1]), max(s_grmax[2], s_grmax[3]));
        int a7 = min(min(s_gcmin[0], s_gcmin[1]), min(s_gcmin[2], s_gcmin[3]));
        int a8 = max(max(s_gcmax[0], s_gcmax[1]), max(s_gcmax[2], s_gcmax[3]));
        ws->cel_part[blk] = celT;              // deterministic partial
        atomicAdd(&ws->tcnt[b], tcT);
        atomicAdd(&ws->gcnt[b], gcT);
        atomicMin(&ws->trmin[b], a1);  atomicMax(&ws->trmax[b], a2);
        atomicMin(&ws->tcmin[b], a3);  atomicMax(&ws->tcmax[b], a4);
        atomicMin(&ws->grmin[b], a5);  atomicMax(&ws->grmax[b], a6);
        atomicMin(&ws->gcmin[b], a7);  atomicMax(&ws->gcmax[b], a8);
    }
}

__device__ __forceinline__ float sqf(float v) { return v * v; }

__global__ __launch_bounds__(256) void wnet_finalize(
        const WsLayout* __restrict__ ws, float* __restrict__ out) {
    // ---- reduce the 2048 deterministic cel partials ----
    __shared__ float s_cel[4];
    float c = 0.0f;
    for (int i = threadIdx.x; i < BB*CHUNKS; i += 256) c += ws->cel_part[i];
    #pragma unroll
    for (int o = 32; o > 0; o >>= 1) c += __shfl_down(c, o);
    const int wid  = threadIdx.x >> 6;
    const int lane = threadIdx.x & 63;
    if (lane == 0) s_cel[wid] = c;
    __syncthreads();

    if (threadIdx.x < 64) {
        const int b = threadIdx.x;
        const bool act = (b < BB);
        unsigned int tcb = act ? ws->tcnt[b] : 0u;
        unsigned int gcb = act ? ws->gcnt[b] : 0u;
        int fl = act ? ((tcb > 0u && gcb > 0u) ? 1 : 0) : 1;
        float dc = 0.0f, dl = 0.0f;
        if (act) {
            const float xrmin = (float)ws->trmin[b], xrmax = (float)ws->trmax[b];
            const float xcmin = (float)ws->tcmin[b], xcmax = (float)ws->tcmax[b];
            const float yrmin = (float)ws->grmin[b], yrmax = (float)ws->grmax[b];
            const float ycmin = (float)ws->gcmin[b], ycmax = (float)ws->gcmax[b];
            // faithful to reference: row coords / W, col coords / H
            const float xcx = (xrmin + xrmax) * 0.5f / (float)WW;
            const float xcy = (xcmin + xcmax) * 0.5f / (float)HH;
            const float xlen = sqf((xrmax - xrmin) / (float)WW) + sqf((xcmax - xcmin) / (float)HH);
            const float gcx = (yrmin + yrmax) * 0.5f / (float)WW;
            const float gcy = (ycmin + ycmax) * 0.5f / (float)HH;
            const float glen = sqf((yrmax - yrmin) / (float)WW) + sqf((ycmax - ycmin) / (float)HH);
            dc = sqf(xcx - gcx) + sqf(xcy - gcy);
            dl = sqf(xlen - glen);
        }
        float tcf = (float)tcb, gcf = (float)gcb;
        #pragma unroll
        for (int o = 32; o > 0; o >>= 1) {
            tcf += __shfl_down(tcf, o);
            gcf += __shfl_down(gcf, o);
            fl = min(fl, __shfl_down(fl, o));
            dc += __shfl_down(dc, o);
            dl += __shfl_down(dl, o);
        }
        if (threadIdx.x == 0) {
            const float celT = s_cel[0] + s_cel[1] + s_cel[2] + s_cel[3];
            const float area = (float)HW * (float)BB;       // 33554432
            const float cel_loss = celT / area;
            float al = (tcf - gcf) / area;
            const float area_loss = al * al;
            const float dist_c = dc / (float)BB;
            const float dist_l = dl / (float)BB;
            out[0] = cel_loss + area_loss + 0.5f * (float)fl * (dist_c + dist_l);
        }
    }
}

extern "C" void kernel_launch(void* const* d_in, const int* in_sizes, int n_in,
                              void* d_out, int out_size, void* d_ws, size_t ws_size,
                              hipStream_t stream) {
    const float* x  = (const float*)d_in[0];
    const int*   gt = (const int*)d_in[1];
    float* out = (float*)d_out;
    WsLayout* ws = (WsLayout*)d_ws;

    hipLaunchKernelGGL(init_ws, dim3(8), dim3(256), 0, stream, ws);
    hipLaunchKernelGGL(wnet_main, dim3(BB*CHUNKS), dim3(THREADS), 0, stream, x, gt, ws);
    hipLaunchKernelGGL(wnet_finalize, dim3(1), dim3(256), 0, stream, ws, out);
}

// Round 3
// 77.275 us; speedup vs baseline: 1.2405x; 1.2405x over previous
//
#include <hip/hip_runtime.h>
#include <math.h>

#define HH 1024
#define WW 1024
#define BB 32
#define HW (HH*WW)                 // 1048576 pixels per sample
#define CHUNKS 64                  // blocks per sample
#define PIXB (HW/CHUNKS)           // 16384 pixels per block
#define THREADS 256
#define ITERS (PIXB/4/THREADS)     // 16 float4 iterations per thread
#define NBLK (BB*CHUNKS)           // 2048 blocks

typedef float f32x4 __attribute__((ext_vector_type(4)));
typedef int   i32x4 __attribute__((ext_vector_type(4)));

struct WsLayout {
    float cel_part[NBLK];
    int tcnt[NBLK], gcnt[NBLK];
    int trmin[NBLK], trmax[NBLK], tcmin[NBLK], tcmax[NBLK];
    int grmin[NBLK], grmax[NBLK], gcmin[NBLK], gcmax[NBLK];
};

__global__ __launch_bounds__(THREADS) void wnet_main(
        const float* __restrict__ x, const int* __restrict__ gt,
        WsLayout* __restrict__ ws) {
    const int blk   = blockIdx.x;
    const int b     = blk >> 6;        // / CHUNKS
    const int chunk = blk & 63;
    const f32x4* __restrict__ x0 = reinterpret_cast<const f32x4*>(x + (size_t)b * 2 * HW);
    const f32x4* __restrict__ x1 = reinterpret_cast<const f32x4*>(x + (size_t)b * 2 * HW + HW);
    const i32x4* __restrict__ g  = reinterpret_cast<const i32x4*>(gt + (size_t)b * HW);
    const int base4    = chunk * (PIXB/4);
    const int wavebase = threadIdx.x & ~63;   // uniform within wave

    float cel = 0.0f;
    // wave-uniform (SGPR) accumulators
    int tc = 0, gc = 0;
    int trmin = HH, trmax = -1, tcmin = WW, tcmax = -1;
    int grmin = HH, grmax = -1, gcmin = WW, gcmax = -1;

    #pragma unroll 4
    for (int it = 0; it < ITERS; ++it) {
        const int idx4 = base4 + it*THREADS + threadIdx.x;
        const f32x4 a  = __builtin_nontemporal_load(&x0[idx4]);
        const f32x4 c  = __builtin_nontemporal_load(&x1[idx4]);
        const i32x4 gv = __builtin_nontemporal_load(&g[idx4]);
        // 256 consecutive pixels per wave-iteration -> same row, uniform col base
        const int p0 = (base4 + it*THREADS + wavebase) << 2;
        const int h  = p0 >> 10;           // row (W=1024)
        const int wb = p0 & 1023;          // col base of lane 0, elem 0

        #pragma unroll
        for (int j = 0; j < 4; ++j) {
            const float xa = a[j];
            const float xc = c[j];
            const bool t = xc > xa;
            const bool m = (gv[j] == 1);
            const unsigned long long bt = __ballot(t);
            const unsigned long long bg = __ballot(m);
            tc += __popcll(bt);
            gc += __popcll(bg);
            if (bt) {  // wave-uniform branch, scalar ops inside
                trmin = min(trmin, h);  trmax = max(trmax, h);
                tcmin = min(tcmin, wb + (__builtin_ctzll(bt) << 2) + j);
                tcmax = max(tcmax, wb + ((63 - __builtin_clzll(bt)) << 2) + j);
            }
            if (bg) {
                grmin = min(grmin, h);  grmax = max(grmax, h);
                gcmin = min(gcmin, wb + (__builtin_ctzll(bg) << 2) + j);
                gcmax = max(gcmax, wb + ((63 - __builtin_clzll(bg)) << 2) + j);
            }
            // cel: softplus(x_other - x_gt), stable form
            const float d = m ? (xa - xc) : (xc - xa);
            cel += fmaxf(d, 0.0f) + __logf(1.0f + __expf(-fabsf(d)));
        }
    }

    // only cel needs a lane reduction
    #pragma unroll
    for (int o = 32; o > 0; o >>= 1) cel += __shfl_down(cel, o);

    __shared__ float s_cel[4];
    __shared__ int   s_v[4][10];
    const int wid  = threadIdx.x >> 6;
    const int lane = threadIdx.x & 63;
    if (lane == 0) {
        s_cel[wid]  = cel;
        s_v[wid][0] = tc;    s_v[wid][1] = gc;
        s_v[wid][2] = trmin; s_v[wid][3] = trmax;
        s_v[wid][4] = tcmin; s_v[wid][5] = tcmax;
        s_v[wid][6] = grmin; s_v[wid][7] = grmax;
        s_v[wid][8] = gcmin; s_v[wid][9] = gcmax;
    }
    __syncthreads();
    if (threadIdx.x == 0) {
        ws->cel_part[blk] = s_cel[0] + s_cel[1] + s_cel[2] + s_cel[3];
        ws->tcnt[blk]  = s_v[0][0] + s_v[1][0] + s_v[2][0] + s_v[3][0];
        ws->gcnt[blk]  = s_v[0][1] + s_v[1][1] + s_v[2][1] + s_v[3][1];
        ws->trmin[blk] = min(min(s_v[0][2], s_v[1][2]), min(s_v[2][2], s_v[3][2]));
        ws->trmax[blk] = max(max(s_v[0][3], s_v[1][3]), max(s_v[2][3], s_v[3][3]));
        ws->tcmin[blk] = min(min(s_v[0][4], s_v[1][4]), min(s_v[2][4], s_v[3][4]));
        ws->tcmax[blk] = max(max(s_v[0][5], s_v[1][5]), max(s_v[2][5], s_v[3][5]));
        ws->grmin[blk] = min(min(s_v[0][6], s_v[1][6]), min(s_v[2][6], s_v[3][6]));
        ws->grmax[blk] = max(max(s_v[0][7], s_v[1][7]), max(s_v[2][7], s_v[3][7]));
        ws->gcmin[blk] = min(min(s_v[0][8], s_v[1][8]), min(s_v[2][8], s_v[3][8]));
        ws->gcmax[blk] = max(max(s_v[0][9], s_v[1][9]), max(s_v[2][9], s_v[3][9]));
    }
}

__device__ __forceinline__ float sqf(float v) { return v * v; }

__global__ __launch_bounds__(256) void wnet_finalize(
        const WsLayout* __restrict__ ws, float* __restrict__ out) {
    __shared__ float s_cel[4];
    __shared__ float s_dc[BB], s_dl[BB];
    __shared__ int   s_tc[BB], s_gc[BB], s_fl[BB];

    // ---- reduce the 2048 deterministic cel partials ----
    float c = 0.0f;
    for (int i = threadIdx.x; i < NBLK; i += 256) c += ws->cel_part[i];
    #pragma unroll
    for (int o = 32; o > 0; o >>= 1) c += __shfl_down(c, o);
    const int wid  = threadIdx.x >> 6;
    const int lane = threadIdx.x & 63;
    if (lane == 0) s_cel[wid] = c;

    // ---- per-sample reduce: 8 threads per sample, 8 chunks each ----
    const int b    = threadIdx.x >> 3;   // 0..31
    const int part = threadIdx.x & 7;    // 0..7
    int tcs = 0, gcs = 0;
    int a1 = HH, a2 = -1, a3 = WW, a4 = -1;   // trans bbox
    int a5 = HH, a6 = -1, a7 = WW, a8 = -1;   // gt bbox
    #pragma unroll
    for (int k = 0; k < 8; ++k) {
        const int idx = b*64 + part*8 + k;
        tcs += ws->tcnt[idx];  gcs += ws->gcnt[idx];
        a1 = min(a1, ws->trmin[idx]);  a2 = max(a2, ws->trmax[idx]);
        a3 = min(a3, ws->tcmin[idx]);  a4 = max(a4, ws->tcmax[idx]);
        a5 = min(a5, ws->grmin[idx]);  a6 = max(a6, ws->grmax[idx]);
        a7 = min(a7, ws->gcmin[idx]);  a8 = max(a8, ws->gcmax[idx]);
    }
    #pragma unroll
    for (int o = 4; o > 0; o >>= 1) {
        tcs += __shfl_down(tcs, o, 8);  gcs += __shfl_down(gcs, o, 8);
        a1 = min(a1, __shfl_down(a1, o, 8));  a2 = max(a2, __shfl_down(a2, o, 8));
        a3 = min(a3, __shfl_down(a3, o, 8));  a4 = max(a4, __shfl_down(a4, o, 8));
        a5 = min(a5, __shfl_down(a5, o, 8));  a6 = max(a6, __shfl_down(a6, o, 8));
        a7 = min(a7, __shfl_down(a7, o, 8));  a8 = max(a8, __shfl_down(a8, o, 8));
    }
    if (part == 0) {
        const float xrmin = (float)a1, xrmax = (float)a2;
        const float xcmin = (float)a3, xcmax = (float)a4;
        const float yrmin = (float)a5, yrmax = (float)a6;
        const float ycmin = (float)a7, ycmax = (float)a8;
        // faithful to reference: row coords / W, col coords / H
        const float xcx  = (xrmin + xrmax) * 0.5f / (float)WW;
        const float xcy  = (xcmin + xcmax) * 0.5f / (float)HH;
        const float xlen = sqf((xrmax - xrmin) / (float)WW) + sqf((xcmax - xcmin) / (float)HH);
        const float gcx  = (yrmin + yrmax) * 0.5f / (float)WW;
        const float gcy  = (ycmin + ycmax) * 0.5f / (float)HH;
        const float glen = sqf((yrmax - yrmin) / (float)WW) + sqf((ycmax - ycmin) / (float)HH);
        s_dc[b] = sqf(xcx - gcx) + sqf(xcy - gcy);
        s_dl[b] = sqf(xlen - glen);
        s_tc[b] = tcs;  s_gc[b] = gcs;
        s_fl[b] = (tcs > 0 && gcs > 0) ? 1 : 0;
    }
    __syncthreads();
    if (threadIdx.x == 0) {
        const float celT = s_cel[0] + s_cel[1] + s_cel[2] + s_cel[3];
        int tcT = 0, gcT = 0, fl = 1;
        float dc = 0.0f, dl = 0.0f;
        for (int i = 0; i < BB; ++i) {
            tcT += s_tc[i];  gcT += s_gc[i];
            fl  &= s_fl[i];
            dc  += s_dc[i];  dl += s_dl[i];
        }
        const float area = (float)HW * (float)BB;       // 33554432
        const float cel_loss = celT / area;
        const float al = ((float)tcT - (float)gcT) / area;
        const float area_loss = al * al;
        const float dist_c = dc / (float)BB;
        const float dist_l = dl / (float)BB;
        out[0] = cel_loss + area_loss + 0.5f * (float)fl * (dist_c + dist_l);
    }
}

extern "C" void kernel_launch(void* const* d_in, const int* in_sizes, int n_in,
                              void* d_out, int out_size, void* d_ws, size_t ws_size,
                              hipStream_t stream) {
    const float* x  = (const float*)d_in[0];
    const int*   gt = (const int*)d_in[1];
    float* out = (float*)d_out;
    WsLayout* ws = (WsLayout*)d_ws;

    hipLaunchKernelGGL(wnet_main, dim3(NBLK), dim3(THREADS), 0, stream, x, gt, ws);
    hipLaunchKernelGGL(wnet_finalize, dim3(1), dim3(256), 0, stream, ws, out);
}